// Round 18
// baseline (1095.877 us; speedup 1.0000x reference)
//
#include <hip/hip_runtime.h>

#define BATCH   512
#define TSTEPS  50
#define NIN     784
#define NHID    800
#define NOUT    10
#define KC      384   // OpenBLAS SGEMM_DEFAULT_Q — panel folds at k=384, 768

typedef float v4f __attribute__((ext_vector_type(4)));

// ---------------------------------------------------------------------------
// Full-K GEMM (NT) for layer 1, k=0..768 in ONE dispatch with IN-REGISTER
// panel fold at k=384:  out = fadd(P1, P2)  (P3 fused in lif_scan_hid1 ->
// total chain ((P1+P2)+P3), bit-exact OpenBLAS).
// Round-14 structure (best measured: 229 us/panel): 128x128 tile, 8x8 micro,
// BK=8, k-major LDS, swizzled B, 256 threads, single-buffer, 2 barriers.
// Accumulators = 32 NAMED float4s (16 part + 16 acc) — named scalars/vec4s
// are the ONLY form this compiler keeps out of scratch (rounds 12-14);
// AGPR-homing of them is free (round 15 proved forcing VGPR is WORSE).
// Requires M%128==0.
// ---------------------------------------------------------------------------
#define ROW_FMA(pl, ph, as)                       \
    pl.x = __fmaf_rn(as, blo.x, pl.x);            \
    pl.y = __fmaf_rn(as, blo.y, pl.y);            \
    pl.z = __fmaf_rn(as, blo.z, pl.z);            \
    pl.w = __fmaf_rn(as, blo.w, pl.w);            \
    ph.x = __fmaf_rn(as, bhi.x, ph.x);            \
    ph.y = __fmaf_rn(as, bhi.y, ph.y);            \
    ph.z = __fmaf_rn(as, bhi.z, ph.z);            \
    ph.w = __fmaf_rn(as, bhi.w, ph.w);

// panel fold: acc <- part (exact copy, no rounding), part <- 0
#define FOLD_ROW(ql, qh, pl, ph)                  \
    ql = pl; qh = ph;                             \
    pl.x = 0.f; pl.y = 0.f; pl.z = 0.f; pl.w = 0.f; \
    ph.x = 0.f; ph.y = 0.f; ph.z = 0.f; ph.w = 0.f;

// epilogue: C = fadd(P1, P2) per element
#define STORE_ROW2(i, ql, qh, pl, ph)                               \
    {   float* crow = Cp + (size_t)(m0 + 8*ty + (i)) * N + cb;      \
        if (cb + 4 <= N) {                                          \
            float4 o; o.x = __fadd_rn(ql.x, pl.x);                  \
            o.y = __fadd_rn(ql.y, pl.y);                            \
            o.z = __fadd_rn(ql.z, pl.z);                            \
            o.w = __fadd_rn(ql.w, pl.w);                            \
            *(float4*)crow = o; }                                   \
        if (cb + 8 <= N) {                                          \
            float4 o; o.x = __fadd_rn(qh.x, ph.x);                  \
            o.y = __fadd_rn(qh.y, ph.y);                            \
            o.z = __fadd_rn(qh.z, ph.z);                            \
            o.w = __fadd_rn(qh.w, ph.w);                            \
            *(float4*)(crow + 4) = o; } }

__global__ __launch_bounds__(256)
void gemm_full_f32(const float* __restrict__ A, const float* __restrict__ B,
                   float* __restrict__ Cp, int M, int N, int K)
{
    __shared__ float As[8][132];   // [k][m]
    __shared__ float Bs[8][188];   // [k][phys(n)], phys = 12*(n>>3)+(n&7)

    const int tid = threadIdx.x;
    const int tx = tid & 15;        // n micro: 8 cols at 8*tx
    const int ty = tid >> 4;        // m micro: 8 rows at 8*ty
    const int m0 = blockIdx.x * 128;
    const int n0 = blockIdx.y * 128;

    const int srow = tid >> 1;          // 0..127
    const int skq  = (tid & 1) * 4;     // 0 or 4
    const int bphys = 12 * (srow >> 3) + (srow & 7);

    const float* Aptr = A + (size_t)(m0 + srow) * K + skq;
    const float* Bptr = B + (size_t)(n0 + srow) * K + skq;
    const bool bval = (n0 + srow) < N;

    // P-part registers (current panel chain)
    float4 p0l = {0,0,0,0}, p0h = {0,0,0,0}, p1l = {0,0,0,0}, p1h = {0,0,0,0};
    float4 p2l = {0,0,0,0}, p2h = {0,0,0,0}, p3l = {0,0,0,0}, p3h = {0,0,0,0};
    float4 p4l = {0,0,0,0}, p4h = {0,0,0,0}, p5l = {0,0,0,0}, p5h = {0,0,0,0};
    float4 p6l = {0,0,0,0}, p6h = {0,0,0,0}, p7l = {0,0,0,0}, p7h = {0,0,0,0};
    // Q-acc registers (closed panel P1)
    float4 q0l = {0,0,0,0}, q0h = {0,0,0,0}, q1l = {0,0,0,0}, q1h = {0,0,0,0};
    float4 q2l = {0,0,0,0}, q2h = {0,0,0,0}, q3l = {0,0,0,0}, q3h = {0,0,0,0};
    float4 q4l = {0,0,0,0}, q4h = {0,0,0,0}, q5l = {0,0,0,0}, q5h = {0,0,0,0};
    float4 q6l = {0,0,0,0}, q6h = {0,0,0,0}, q7l = {0,0,0,0}, q7h = {0,0,0,0};

    float4 av = *(const float4*)(Aptr);
    float4 bv = bval ? *(const float4*)(Bptr) : make_float4(0.f,0.f,0.f,0.f);

    const int KE = 2 * KC;   // 768
    for (int k0 = 0; k0 < KE; k0 += 8) {
        __syncthreads();
        As[skq+0][srow] = av.x; As[skq+1][srow] = av.y;
        As[skq+2][srow] = av.z; As[skq+3][srow] = av.w;
        Bs[skq+0][bphys] = bv.x; Bs[skq+1][bphys] = bv.y;
        Bs[skq+2][bphys] = bv.z; Bs[skq+3][bphys] = bv.w;
        __syncthreads();

        if (k0 + 8 < KE) {
            av = *(const float4*)(Aptr + k0 + 8);
            bv = bval ? *(const float4*)(Bptr + k0 + 8)
                      : make_float4(0.f,0.f,0.f,0.f);
        }

        // in-register panel fold at k=384 (uniform branch, exact copy)
        if (k0 == KC) {
            FOLD_ROW(q0l, q0h, p0l, p0h)
            FOLD_ROW(q1l, q1h, p1l, p1h)
            FOLD_ROW(q2l, q2h, p2l, p2h)
            FOLD_ROW(q3l, q3h, p3l, p3h)
            FOLD_ROW(q4l, q4h, p4l, p4h)
            FOLD_ROW(q5l, q5h, p5l, p5h)
            FOLD_ROW(q6l, q6h, p6l, p6h)
            FOLD_ROW(q7l, q7h, p7l, p7h)
        }

        #pragma unroll
        for (int kk = 0; kk < 8; ++kk) {
            const float4 alo = *(const float4*)&As[kk][8*ty];
            const float4 ahi = *(const float4*)&As[kk][8*ty + 4];
            const float4 blo = *(const float4*)&Bs[kk][12*tx];
            const float4 bhi = *(const float4*)&Bs[kk][12*tx + 4];
            ROW_FMA(p0l, p0h, alo.x)
            ROW_FMA(p1l, p1h, alo.y)
            ROW_FMA(p2l, p2h, alo.z)
            ROW_FMA(p3l, p3h, alo.w)
            ROW_FMA(p4l, p4h, ahi.x)
            ROW_FMA(p5l, p5h, ahi.y)
            ROW_FMA(p6l, p6h, ahi.z)
            ROW_FMA(p7l, p7h, ahi.w)
        }
    }

    const int cb = n0 + 8 * tx;
    STORE_ROW2(0, q0l, q0h, p0l, p0h)
    STORE_ROW2(1, q1l, q1h, p1l, p1h)
    STORE_ROW2(2, q2l, q2h, p2l, p2h)
    STORE_ROW2(3, q3l, q3h, p3l, p3h)
    STORE_ROW2(4, q4l, q4h, p4l, p4h)
    STORE_ROW2(5, q5l, q5h, p5l, p5h)
    STORE_ROW2(6, q6l, q6h, p6l, p6h)
    STORE_ROW2(7, q7l, q7h, p7l, p7h)
}

// ---------------------------------------------------------------------------
// 800x800 transpose: W2T[k][n] = W2[n][k]
// ---------------------------------------------------------------------------
__global__ __launch_bounds__(256)
void transpose800(const float* __restrict__ W2, float* __restrict__ W2T)
{
    __shared__ float t[32][33];
    const int tx  = threadIdx.x & 31;
    const int ty8 = threadIdx.x >> 5;
    const int bx = blockIdx.x * 32, by = blockIdx.y * 32;

    #pragma unroll
    for (int r = 0; r < 4; ++r) {
        int a = ty8 + r * 8;
        t[a][tx] = W2[(size_t)(by + a) * 800 + bx + tx];
    }
    __syncthreads();
    #pragma unroll
    for (int r = 0; r < 4; ++r) {
        int a = ty8 + r * 8;
        W2T[(size_t)(bx + a) * 800 + by + tx] = t[tx][a];
    }
}

// ---------------------------------------------------------------------------
// Layer-1 LIF scan with fused P3 (k=768..784 chain).
// z = (P1+P2) [from gemm_full] then z = fadd(z, P3); m = ((0.95f*m)+z)+b.
// ---------------------------------------------------------------------------
__global__ __launch_bounds__(256)
void lif_scan_hid1(const float* __restrict__ Z0,   // (P1+P2)
                   const float* __restrict__ xc,   // x + t0*BATCH*NIN
                   const float* __restrict__ W1,
                   const float* __restrict__ bias,
                   const float* __restrict__ budget,
                   float* __restrict__ mcarry,
                   float* __restrict__ Sout,
                   unsigned long long* __restrict__ bm,
                   int CT, int t0)
{
    __shared__ float W1s[NHID][17];

    const int b = blockIdx.x;
    const int tid = threadIdx.x;
    const int lane = tid & 63;
    const int wave = tid >> 6;

    for (int q = tid; q < NHID * 16; q += 256)
        W1s[q >> 4][q & 15] = W1[(size_t)(q >> 4) * NIN + 768 + (q & 15)];
    __syncthreads();

    float m[4], thr[4], bj[4];
    bool val[4];
    int jjv[4];
    #pragma unroll
    for (int c = 0; c < 4; ++c) {
        const int j = c * 256 + tid;
        val[c] = (j < NHID);
        const int jj = val[c] ? j : 0;
        jjv[c] = jj;
        float bu = budget[jj];
        bu = fminf(fmaxf(bu, 0.01f), 1.0f);
        thr[c] = __fdiv_rn(1.0f, bu);
        bj[c]  = bias[jj];
        m[c]   = mcarry[b * NHID + jj];
    }

    for (int ct = 0; ct < CT; ++ct) {
        const size_t zbase = (size_t)ct * (BATCH * NHID) + (size_t)b * NHID;
        const size_t sbase = (size_t)(t0 + ct) * (BATCH * NHID) + (size_t)b * NHID;
        const float* xr = xc + ((size_t)ct * BATCH + b) * NIN + 768;
        const float4 x0 = *(const float4*)(xr);
        const float4 x1 = *(const float4*)(xr + 4);
        const float4 x2 = *(const float4*)(xr + 8);
        const float4 x3 = *(const float4*)(xr + 12);

        #pragma unroll
        for (int c = 0; c < 4; ++c) {
            const int j = c * 256 + tid;
            bool sp = false;
            if (val[c]) {
                const int jj = jjv[c];
                float z = __builtin_nontemporal_load(Z0 + zbase + j);
                float p3 = 0.0f;
                p3 = __fmaf_rn(x0.x, W1s[jj][0],  p3);
                p3 = __fmaf_rn(x0.y, W1s[jj][1],  p3);
                p3 = __fmaf_rn(x0.z, W1s[jj][2],  p3);
                p3 = __fmaf_rn(x0.w, W1s[jj][3],  p3);
                p3 = __fmaf_rn(x1.x, W1s[jj][4],  p3);
                p3 = __fmaf_rn(x1.y, W1s[jj][5],  p3);
                p3 = __fmaf_rn(x1.z, W1s[jj][6],  p3);
                p3 = __fmaf_rn(x1.w, W1s[jj][7],  p3);
                p3 = __fmaf_rn(x2.x, W1s[jj][8],  p3);
                p3 = __fmaf_rn(x2.y, W1s[jj][9],  p3);
                p3 = __fmaf_rn(x2.z, W1s[jj][10], p3);
                p3 = __fmaf_rn(x2.w, W1s[jj][11], p3);
                p3 = __fmaf_rn(x3.x, W1s[jj][12], p3);
                p3 = __fmaf_rn(x3.y, W1s[jj][13], p3);
                p3 = __fmaf_rn(x3.z, W1s[jj][14], p3);
                p3 = __fmaf_rn(x3.w, W1s[jj][15], p3);
                z = __fadd_rn(z, p3);

                float mm = __fadd_rn(__fadd_rn(__fmul_rn(0.95f, m[c]), z), bj[c]);
                sp = (mm > thr[c]);
                m[c] = sp ? 0.0f : mm;
                __builtin_nontemporal_store(sp ? 1.0f : 0.0f, Sout + sbase + j);
            }
            unsigned long long bits = __ballot(sp);
            if (lane == 0) {
                const int W = c * 4 + wave;
                if (W < 13)
                    bm[((size_t)ct * BATCH + b) * 13 + W] = bits;
            }
        }
    }
    #pragma unroll
    for (int c = 0; c < 4; ++c)
        if (val[c]) mcarry[b * NHID + c * 256 + tid] = m[c];
}

// ---------------------------------------------------------------------------
// Layer-2 LIF scan (single-panel z), no bitmask.
// ---------------------------------------------------------------------------
__global__ __launch_bounds__(256)
void lif_scan_hid2(const float* __restrict__ Z0,
                   const float* __restrict__ bias,
                   const float* __restrict__ budget,
                   float* __restrict__ mcarry,
                   float* __restrict__ Sout,
                   int CT, int t0)
{
    const int b = blockIdx.x;
    const int tid = threadIdx.x;

    float m[4], thr[4], bj[4];
    bool val[4];
    #pragma unroll
    for (int c = 0; c < 4; ++c) {
        const int j = c * 256 + tid;
        val[c] = (j < NHID);
        const int jj = val[c] ? j : 0;
        float bu = budget[jj];
        bu = fminf(fmaxf(bu, 0.01f), 1.0f);
        thr[c] = __fdiv_rn(1.0f, bu);
        bj[c]  = bias[jj];
        m[c]   = mcarry[b * NHID + jj];
    }

    for (int ct = 0; ct < CT; ++ct) {
        const size_t zbase = (size_t)ct * (BATCH * NHID) + (size_t)b * NHID;
        const size_t sbase = (size_t)(t0 + ct) * (BATCH * NHID) + (size_t)b * NHID;
        #pragma unroll
        for (int c = 0; c < 4; ++c) {
            const int j = c * 256 + tid;
            if (val[c]) {
                float z = __builtin_nontemporal_load(Z0 + zbase + j);
                float mm = __fadd_rn(__fadd_rn(__fmul_rn(0.95f, m[c]), z), bj[c]);
                bool sp = (mm > thr[c]);
                m[c] = sp ? 0.0f : mm;
                __builtin_nontemporal_store(sp ? 1.0f : 0.0f, Sout + sbase + j);
            }
        }
    }
    #pragma unroll
    for (int c = 0; c < 4; ++c)
        if (val[c]) mcarry[b * NHID + c * 256 + tid] = m[c];
}

// ---------------------------------------------------------------------------
// Sparse spike GEMM — round-6 proven version (~276 us, AT its L2 roofline:
// 9.5 GB / 34.5 TB/s). Block per row; bitmask -> ordered k-list in LDS,
// wave-uniform walk; panel folds tracked by k index. Do not touch.
// ---------------------------------------------------------------------------
__global__ __launch_bounds__(256)
void spmm_spikes(const unsigned long long* __restrict__ bm, // [rows][13]
                 const float* __restrict__ W2T,             // [800][800]
                 float* __restrict__ Z,                     // [rows][800]
                 int rows)
{
    __shared__ unsigned long long wbuf[13];
    __shared__ unsigned short list[NHID];
    __shared__ int offs[14];

    const int tid = threadIdx.x;
    const int lane = tid & 63;
    const int wave = tid >> 6;
    const int row = blockIdx.x;

    if (tid < 13) wbuf[tid] = bm[(size_t)row * 13 + tid];
    __syncthreads();
    if (tid == 0) {
        int o = 0;
        for (int w = 0; w < 13; ++w) { offs[w] = o; o += __popcll(wbuf[w]); }
        offs[13] = o;
    }
    __syncthreads();
    for (int W = wave; W < 13; W += 4) {
        const unsigned long long bits = wbuf[W];
        const int pre = __popcll(bits & ((1ull << lane) - 1ull));
        if ((bits >> lane) & 1ull)
            list[offs[W] + pre] = (unsigned short)(W * 64 + lane);
    }
    __syncthreads();
    const int nnz = offs[13];

    if (tid < 200) {
        const int n = 4 * tid;
        float p0 = 0.f, p1 = 0.f, p2 = 0.f, p3 = 0.f;
        float a0 = 0.f, a1 = 0.f, a2 = 0.f, a3 = 0.f;
        int p = 0, nextb = KC;          // 384 then 768 then "never"
        for (int i = 0; i < nnz; ++i) {
            const int k = list[i];
            while (k >= nextb) {
                if (p == 0) { a0 = p0; a1 = p1; a2 = p2; a3 = p3; }
                else {
                    a0 = __fadd_rn(a0, p0); a1 = __fadd_rn(a1, p1);
                    a2 = __fadd_rn(a2, p2); a3 = __fadd_rn(a3, p3);
                }
                p0 = p1 = p2 = p3 = 0.f; ++p;
                nextb = (nextb == KC) ? 2 * KC : 100000;
            }
            const float4 w = *(const float4*)(W2T + (size_t)k * NHID + n);
            p0 = __fadd_rn(p0, w.x); p1 = __fadd_rn(p1, w.y);
            p2 = __fadd_rn(p2, w.z); p3 = __fadd_rn(p3, w.w);
        }
        while (p < 3) {                 // close remaining panels (K=800 -> 3)
            if (p == 0) { a0 = p0; a1 = p1; a2 = p2; a3 = p3; }
            else {
                a0 = __fadd_rn(a0, p0); a1 = __fadd_rn(a1, p1);
                a2 = __fadd_rn(a2, p2); a3 = __fadd_rn(a3, p3);
            }
            p0 = p1 = p2 = p3 = 0.f; ++p;
        }
        *(float4*)(Z + (size_t)row * NHID + n) = make_float4(a0, a1, a2, a3);
    }
}

// ---------------------------------------------------------------------------
// Layer-3 GEMM, float4 loads, chain preserved (folds at float4 idx 96/192).
// ---------------------------------------------------------------------------
__global__ __launch_bounds__(256)
void gemm3_f32(const float* __restrict__ S2, const float* __restrict__ W3,
               float* __restrict__ Z3, int rows)
{
    int gid = blockIdx.x * 256 + threadIdx.x;
    if (gid >= rows * NOUT) return;
    const int m = gid / NOUT;
    const int nn = gid % NOUT;
    const float* a = S2 + (size_t)m * NHID;
    const float* wr = W3 + (size_t)nn * NHID;

    float part = 0.0f, acc = 0.0f;
    int p = 0;
    for (int i = 0; i < NHID / 4; ++i) {
        if (i == 96 || i == 192) {
            acc = (p == 0) ? part : __fadd_rn(acc, part);
            part = 0.0f; ++p;
        }
        const v4f a4 = __builtin_nontemporal_load((const v4f*)(a + 4 * i));
        const float4 w4 = *(const float4*)(wr + 4 * i);
        part = __fmaf_rn(a4.x, w4.x, part);
        part = __fmaf_rn(a4.y, w4.y, part);
        part = __fmaf_rn(a4.z, w4.z, part);
        part = __fmaf_rn(a4.w, w4.w, part);
    }
    acc = (p == 0) ? part : __fadd_rn(acc, part);
    Z3[gid] = acc;
}

// ---------------------------------------------------------------------------
__global__ __launch_bounds__(256)
void lif_scan_small(const float* __restrict__ Z, const float* __restrict__ bias,
                    float* __restrict__ mcarry, float* __restrict__ Sout,
                    int CT, int t0)
{
    const int idx = blockIdx.x * blockDim.x + threadIdx.x;
    const int total = BATCH * NOUT;
    if (idx >= total) return;
    const int j = idx % NOUT;
    const float thr = 1.0f;
    const float bj = bias[j];

    float m = mcarry[idx];
    for (int ct = 0; ct < CT; ++ct) {
        float z = Z[(size_t)ct * total + idx];
        m = __fadd_rn(__fadd_rn(__fmul_rn(0.95f, m), z), bj);
        float s;
        if (m > thr) { s = 1.0f; m = 0.0f; }
        else         { s = 0.0f; }
        Sout[(size_t)(t0 + ct) * total + idx] = s;
    }
    mcarry[idx] = m;
}

// ---------------------------------------------------------------------------
__global__ __launch_bounds__(256)
void sum_t(const float* __restrict__ S3, float* __restrict__ out0)
{
    const int idx = blockIdx.x * blockDim.x + threadIdx.x;
    if (idx >= BATCH * NOUT) return;
    float s = 0.0f;
    for (int t = 0; t < TSTEPS; ++t)
        s += S3[(size_t)t * BATCH * NOUT + idx];
    out0[idx] = s;
}

// ---------------------------------------------------------------------------
extern "C" void kernel_launch(void* const* d_in, const int* in_sizes, int n_in,
                              void* d_out, int out_size, void* d_ws, size_t ws_size,
                              hipStream_t stream)
{
    const float* x       = (const float*)d_in[0];
    const float* W1      = (const float*)d_in[1];
    const float* b1      = (const float*)d_in[2];
    const float* W2      = (const float*)d_in[3];
    const float* b2      = (const float*)d_in[4];
    const float* W3      = (const float*)d_in[5];
    const float* b3      = (const float*)d_in[6];
    const float* budget1 = (const float*)d_in[7];
    const float* budget2 = (const float*)d_in[8];

    float* out  = (float*)d_out;
    float* out0 = out;
    float* out1 = out0 + BATCH * NOUT;
    float* out2 = out1 + (size_t)TSTEPS * BATCH * NHID;
    float* out3 = out2 + (size_t)TSTEPS * BATCH * NHID;

    const size_t nBH = (size_t)BATCH * NHID;     // 409600
    const size_t nBO = (size_t)BATCH * NOUT;     // 5120
    float* m1c = (float*)d_ws;
    float* m2c = m1c + nBH;
    float* m3c = m2c + nBH;
    float* w2t = m3c + nBO;
    unsigned long long* bmask = (unsigned long long*)(w2t + (size_t)NHID * NHID);
    float* Z = (float*)(bmask + (size_t)TSTEPS * BATCH * 13);

    const size_t fixedF = 2 * nBH + nBO + (size_t)NHID * NHID
                        + (size_t)TSTEPS * BATCH * 13 * 2;
    size_t availF = (ws_size / 4 > fixedF) ? (ws_size / 4 - fixedF) : 0;
    // per timestep: 1 Z buffer (layer 1 P1+P2, reused by layer 2) + Z3
    const size_t perT = (size_t)BATCH * (NHID + NOUT);
    int CT = (int)(availF / perT);
    if (CT > TSTEPS) CT = TSTEPS;
    if (CT < 1) CT = 1;

    hipMemsetAsync(d_ws, 0, (2 * nBH + nBO) * sizeof(float), stream);

    {
        dim3 tg(25, 25);
        transpose800<<<tg, 256, 0, stream>>>(W2, w2t);
    }

    for (int t0 = 0; t0 < TSTEPS; t0 += CT) {
        int ct = TSTEPS - t0 < CT ? TSTEPS - t0 : CT;
        int Mrows = ct * BATCH;
        const size_t pstride = (size_t)ct * BATCH * NHID;
        float* Zp0 = Z;
        float* Z3  = Z + pstride;
        const float* xc = x + (size_t)t0 * BATCH * NIN;

        // layer 1: ONE dispatch, k=0..768, in-register fold (P3 fused in lif)
        {
            dim3 grid(Mrows / 128, (NHID + 127) / 128);
            gemm_full_f32<<<grid, 256, 0, stream>>>(xc, W1, Zp0, Mrows, NHID, NIN);
        }
        lif_scan_hid1<<<BATCH, 256, 0, stream>>>(
            Zp0, xc, W1, b1, budget1, m1c, out1, bmask, ct, t0);

        // layer 2: sparse Z = s1_chunk @ W2^T via bitmask (1 row/block)
        spmm_spikes<<<Mrows, 256, 0, stream>>>(bmask, w2t, Zp0, Mrows);
        lif_scan_hid2<<<BATCH, 256, 0, stream>>>(
            Zp0, b2, budget2, m2c, out2, ct, t0);

        // layer 3
        gemm3_f32<<<(Mrows * NOUT + 255) / 256, 256, 0, stream>>>(
            out2 + (size_t)t0 * BATCH * NHID, W3, Z3, Mrows);
        lif_scan_small<<<(BATCH * NOUT + 255) / 256, 256, 0, stream>>>(
            Z3, b3, m3c, out3, ct, t0);
    }

    sum_t<<<(BATCH * NOUT + 255) / 256, 256, 0, stream>>>(out3, out0);
}

// Round 19
// 833.026 us; speedup vs baseline: 1.3155x; 1.3155x over previous
//
#include <hip/hip_runtime.h>

#define BATCH   512
#define TSTEPS  50
#define NIN     784
#define NHID    800
#define NOUT    10
#define KC      384   // OpenBLAS SGEMM_DEFAULT_Q — panel folds at k=384, 768

typedef float v4f __attribute__((ext_vector_type(4)));

// ---------------------------------------------------------------------------
// Panel GEMM (NT): ONE KC-panel ascending-k FMA chain per output element.
// 128x128 tile, 8x8 micro, BK=8, k-major LDS, swizzled B, named-float4
// accumulators, LDS double-buffer. BEST MEASURED: 231 us/panel (round 16).
// Ledger of failed alternatives: 8x4 (489/2panels-worth), 8x8+launch_bounds4
// (spill, 2744), BK=16 (590), asm v_fmac (250), BN=160 (297), merged full-K
// (VGPR 180, occ 10.8%, 808). Do not touch without a new mechanism.
// Requires M%128==0, (ke-ks)%8==0.
// ---------------------------------------------------------------------------
#define ROW_FMA(pl, ph, as)                       \
    pl.x = __fmaf_rn(as, blo.x, pl.x);            \
    pl.y = __fmaf_rn(as, blo.y, pl.y);            \
    pl.z = __fmaf_rn(as, blo.z, pl.z);            \
    pl.w = __fmaf_rn(as, blo.w, pl.w);            \
    ph.x = __fmaf_rn(as, bhi.x, ph.x);            \
    ph.y = __fmaf_rn(as, bhi.y, ph.y);            \
    ph.z = __fmaf_rn(as, bhi.z, ph.z);            \
    ph.w = __fmaf_rn(as, bhi.w, ph.w);

#define STORE_ROW(i, pl, ph)                                        \
    {   float* crow = Cp + (size_t)(m0 + 8*ty + (i)) * N + cb;      \
        if (cb + 4 <= N) *(float4*)crow = pl;                       \
        if (cb + 8 <= N) *(float4*)(crow + 4) = ph; }

__global__ __launch_bounds__(256, 2)
void gemm_panel_f32(const float* __restrict__ A, const float* __restrict__ B,
                    float* __restrict__ Cp, int M, int N, int K,
                    int ks, int ke)
{
    __shared__ float As[2][8][132];   // [buf][k][m]
    __shared__ float Bs[2][8][188];   // [buf][k][phys(n)], phys=12*(n>>3)+(n&7)

    const int tid = threadIdx.x;
    const int tx = tid & 15;        // n micro: 8 cols at 8*tx
    const int ty = tid >> 4;        // m micro: 8 rows at 8*ty
    const int m0 = blockIdx.x * 128;
    const int n0 = blockIdx.y * 128;

    const int srow = tid >> 1;          // 0..127
    const int skq  = (tid & 1) * 4;     // 0 or 4
    const int bphys = 12 * (srow >> 3) + (srow & 7);

    const float* Aptr = A + (size_t)(m0 + srow) * K + skq;
    const float* Bptr = B + (size_t)(n0 + srow) * K + skq;
    const bool bval = (n0 + srow) < N;

    float4 p0l = {0,0,0,0}, p0h = {0,0,0,0}, p1l = {0,0,0,0}, p1h = {0,0,0,0};
    float4 p2l = {0,0,0,0}, p2h = {0,0,0,0}, p3l = {0,0,0,0}, p3h = {0,0,0,0};
    float4 p4l = {0,0,0,0}, p4h = {0,0,0,0}, p5l = {0,0,0,0}, p5h = {0,0,0,0};
    float4 p6l = {0,0,0,0}, p6h = {0,0,0,0}, p7l = {0,0,0,0}, p7h = {0,0,0,0};

    // prologue: chunk ks -> buf 0
    {
        float4 av = *(const float4*)(Aptr + ks);
        float4 bv = bval ? *(const float4*)(Bptr + ks)
                         : make_float4(0.f,0.f,0.f,0.f);
        As[0][skq+0][srow] = av.x; As[0][skq+1][srow] = av.y;
        As[0][skq+2][srow] = av.z; As[0][skq+3][srow] = av.w;
        Bs[0][skq+0][bphys] = bv.x; Bs[0][skq+1][bphys] = bv.y;
        Bs[0][skq+2][bphys] = bv.z; Bs[0][skq+3][bphys] = bv.w;
    }
    __syncthreads();

    int cur = 0;
    for (int k0 = ks; k0 < ke; k0 += 8) {
        const bool more = (k0 + 8 < ke);

        // prefetch next chunk into registers (issue before compute)
        float4 av, bv;
        if (more) {
            av = *(const float4*)(Aptr + k0 + 8);
            bv = bval ? *(const float4*)(Bptr + k0 + 8)
                      : make_float4(0.f,0.f,0.f,0.f);
        }

        #pragma unroll
        for (int kk = 0; kk < 8; ++kk) {
            const float4 alo = *(const float4*)&As[cur][kk][8*ty];
            const float4 ahi = *(const float4*)&As[cur][kk][8*ty + 4];
            const float4 blo = *(const float4*)&Bs[cur][kk][12*tx];
            const float4 bhi = *(const float4*)&Bs[cur][kk][12*tx + 4];
            ROW_FMA(p0l, p0h, alo.x)
            ROW_FMA(p1l, p1h, alo.y)
            ROW_FMA(p2l, p2h, alo.z)
            ROW_FMA(p3l, p3h, alo.w)
            ROW_FMA(p4l, p4h, ahi.x)
            ROW_FMA(p5l, p5h, ahi.y)
            ROW_FMA(p6l, p6h, ahi.z)
            ROW_FMA(p7l, p7h, ahi.w)
        }

        if (more) {
            const int nx = cur ^ 1;
            As[nx][skq+0][srow] = av.x; As[nx][skq+1][srow] = av.y;
            As[nx][skq+2][srow] = av.z; As[nx][skq+3][srow] = av.w;
            Bs[nx][skq+0][bphys] = bv.x; Bs[nx][skq+1][bphys] = bv.y;
            Bs[nx][skq+2][bphys] = bv.z; Bs[nx][skq+3][bphys] = bv.w;
            __syncthreads();
        }
        cur ^= 1;
    }

    const int cb = n0 + 8 * tx;
    STORE_ROW(0, p0l, p0h)
    STORE_ROW(1, p1l, p1h)
    STORE_ROW(2, p2l, p2h)
    STORE_ROW(3, p3l, p3h)
    STORE_ROW(4, p4l, p4h)
    STORE_ROW(5, p5l, p5h)
    STORE_ROW(6, p6l, p6h)
    STORE_ROW(7, p7l, p7h)
}

// ---------------------------------------------------------------------------
// 800x800 transpose: W2T[k][n] = W2[n][k]
// ---------------------------------------------------------------------------
__global__ __launch_bounds__(256)
void transpose800(const float* __restrict__ W2, float* __restrict__ W2T)
{
    __shared__ float t[32][33];
    const int tx  = threadIdx.x & 31;
    const int ty8 = threadIdx.x >> 5;
    const int bx = blockIdx.x * 32, by = blockIdx.y * 32;

    #pragma unroll
    for (int r = 0; r < 4; ++r) {
        int a = ty8 + r * 8;
        t[a][tx] = W2[(size_t)(by + a) * 800 + bx + tx];
    }
    __syncthreads();
    #pragma unroll
    for (int r = 0; r < 4; ++r) {
        int a = ty8 + r * 8;
        W2T[(size_t)(bx + a) * 800 + by + tx] = t[tx][a];
    }
}

// ---------------------------------------------------------------------------
// Layer-1 LIF scan with fused P3 (k=768..784 chain) — proven round 14.
// z = ((P1 + P2) + P3); m = ((0.95f*m)+z)+b; s=(m>thr); mult reset; bitmask.
// ---------------------------------------------------------------------------
__global__ __launch_bounds__(256)
void lif_scan_hid1(const float* __restrict__ Z0,
                   const float* __restrict__ Z1,
                   const float* __restrict__ xc,   // x + t0*BATCH*NIN
                   const float* __restrict__ W1,
                   const float* __restrict__ bias,
                   const float* __restrict__ budget,
                   float* __restrict__ mcarry,
                   float* __restrict__ Sout,
                   unsigned long long* __restrict__ bm,
                   int CT, int t0)
{
    __shared__ float W1s[NHID][17];

    const int b = blockIdx.x;
    const int tid = threadIdx.x;
    const int lane = tid & 63;
    const int wave = tid >> 6;

    for (int q = tid; q < NHID * 16; q += 256)
        W1s[q >> 4][q & 15] = W1[(size_t)(q >> 4) * NIN + 768 + (q & 15)];
    __syncthreads();

    float m[4], thr[4], bj[4];
    bool val[4];
    int jjv[4];
    #pragma unroll
    for (int c = 0; c < 4; ++c) {
        const int j = c * 256 + tid;
        val[c] = (j < NHID);
        const int jj = val[c] ? j : 0;
        jjv[c] = jj;
        float bu = budget[jj];
        bu = fminf(fmaxf(bu, 0.01f), 1.0f);
        thr[c] = __fdiv_rn(1.0f, bu);
        bj[c]  = bias[jj];
        m[c]   = mcarry[b * NHID + jj];
    }

    for (int ct = 0; ct < CT; ++ct) {
        const size_t zbase = (size_t)ct * (BATCH * NHID) + (size_t)b * NHID;
        const size_t sbase = (size_t)(t0 + ct) * (BATCH * NHID) + (size_t)b * NHID;
        const float* xr = xc + ((size_t)ct * BATCH + b) * NIN + 768;
        const float4 x0 = *(const float4*)(xr);
        const float4 x1 = *(const float4*)(xr + 4);
        const float4 x2 = *(const float4*)(xr + 8);
        const float4 x3 = *(const float4*)(xr + 12);

        #pragma unroll
        for (int c = 0; c < 4; ++c) {
            const int j = c * 256 + tid;
            bool sp = false;
            if (val[c]) {
                const int jj = jjv[c];
                float z = __fadd_rn(__builtin_nontemporal_load(Z0 + zbase + j),
                                    __builtin_nontemporal_load(Z1 + zbase + j));
                float p3 = 0.0f;
                p3 = __fmaf_rn(x0.x, W1s[jj][0],  p3);
                p3 = __fmaf_rn(x0.y, W1s[jj][1],  p3);
                p3 = __fmaf_rn(x0.z, W1s[jj][2],  p3);
                p3 = __fmaf_rn(x0.w, W1s[jj][3],  p3);
                p3 = __fmaf_rn(x1.x, W1s[jj][4],  p3);
                p3 = __fmaf_rn(x1.y, W1s[jj][5],  p3);
                p3 = __fmaf_rn(x1.z, W1s[jj][6],  p3);
                p3 = __fmaf_rn(x1.w, W1s[jj][7],  p3);
                p3 = __fmaf_rn(x2.x, W1s[jj][8],  p3);
                p3 = __fmaf_rn(x2.y, W1s[jj][9],  p3);
                p3 = __fmaf_rn(x2.z, W1s[jj][10], p3);
                p3 = __fmaf_rn(x2.w, W1s[jj][11], p3);
                p3 = __fmaf_rn(x3.x, W1s[jj][12], p3);
                p3 = __fmaf_rn(x3.y, W1s[jj][13], p3);
                p3 = __fmaf_rn(x3.z, W1s[jj][14], p3);
                p3 = __fmaf_rn(x3.w, W1s[jj][15], p3);
                z = __fadd_rn(z, p3);

                float mm = __fadd_rn(__fadd_rn(__fmul_rn(0.95f, m[c]), z), bj[c]);
                sp = (mm > thr[c]);
                m[c] = sp ? 0.0f : mm;
                __builtin_nontemporal_store(sp ? 1.0f : 0.0f, Sout + sbase + j);
            }
            unsigned long long bits = __ballot(sp);
            if (lane == 0) {
                const int W = c * 4 + wave;
                if (W < 13)
                    bm[((size_t)ct * BATCH + b) * 13 + W] = bits;
            }
        }
    }
    #pragma unroll
    for (int c = 0; c < 4; ++c)
        if (val[c]) mcarry[b * NHID + c * 256 + tid] = m[c];
}

// ---------------------------------------------------------------------------
// Layer-2 LIF scan (single-panel z), no bitmask.
// ---------------------------------------------------------------------------
__global__ __launch_bounds__(256)
void lif_scan_hid2(const float* __restrict__ Z0,
                   const float* __restrict__ bias,
                   const float* __restrict__ budget,
                   float* __restrict__ mcarry,
                   float* __restrict__ Sout,
                   int CT, int t0)
{
    const int b = blockIdx.x;
    const int tid = threadIdx.x;

    float m[4], thr[4], bj[4];
    bool val[4];
    #pragma unroll
    for (int c = 0; c < 4; ++c) {
        const int j = c * 256 + tid;
        val[c] = (j < NHID);
        const int jj = val[c] ? j : 0;
        float bu = budget[jj];
        bu = fminf(fmaxf(bu, 0.01f), 1.0f);
        thr[c] = __fdiv_rn(1.0f, bu);
        bj[c]  = bias[jj];
        m[c]   = mcarry[b * NHID + jj];
    }

    for (int ct = 0; ct < CT; ++ct) {
        const size_t zbase = (size_t)ct * (BATCH * NHID) + (size_t)b * NHID;
        const size_t sbase = (size_t)(t0 + ct) * (BATCH * NHID) + (size_t)b * NHID;
        #pragma unroll
        for (int c = 0; c < 4; ++c) {
            const int j = c * 256 + tid;
            if (val[c]) {
                float z = __builtin_nontemporal_load(Z0 + zbase + j);
                float mm = __fadd_rn(__fadd_rn(__fmul_rn(0.95f, m[c]), z), bj[c]);
                bool sp = (mm > thr[c]);
                m[c] = sp ? 0.0f : mm;
                __builtin_nontemporal_store(sp ? 1.0f : 0.0f, Sout + sbase + j);
            }
        }
    }
    #pragma unroll
    for (int c = 0; c < 4; ++c)
        if (val[c]) mcarry[b * NHID + c * 256 + tid] = m[c];
}

// ---------------------------------------------------------------------------
// Sparse spike GEMM — round-6 proven version (~276 us, AT its L2 roofline:
// 9.5 GB / 34.5 TB/s). Block per row; bitmask -> ordered k-list in LDS,
// wave-uniform walk; panel folds tracked by k index. Do not touch.
// ---------------------------------------------------------------------------
__global__ __launch_bounds__(256)
void spmm_spikes(const unsigned long long* __restrict__ bm, // [rows][13]
                 const float* __restrict__ W2T,             // [800][800]
                 float* __restrict__ Z,                     // [rows][800]
                 int rows)
{
    __shared__ unsigned long long wbuf[13];
    __shared__ unsigned short list[NHID];
    __shared__ int offs[14];

    const int tid = threadIdx.x;
    const int lane = tid & 63;
    const int wave = tid >> 6;
    const int row = blockIdx.x;

    if (tid < 13) wbuf[tid] = bm[(size_t)row * 13 + tid];
    __syncthreads();
    if (tid == 0) {
        int o = 0;
        for (int w = 0; w < 13; ++w) { offs[w] = o; o += __popcll(wbuf[w]); }
        offs[13] = o;
    }
    __syncthreads();
    for (int W = wave; W < 13; W += 4) {
        const unsigned long long bits = wbuf[W];
        const int pre = __popcll(bits & ((1ull << lane) - 1ull));
        if ((bits >> lane) & 1ull)
            list[offs[W] + pre] = (unsigned short)(W * 64 + lane);
    }
    __syncthreads();
    const int nnz = offs[13];

    if (tid < 200) {
        const int n = 4 * tid;
        float p0 = 0.f, p1 = 0.f, p2 = 0.f, p3 = 0.f;
        float a0 = 0.f, a1 = 0.f, a2 = 0.f, a3 = 0.f;
        int p = 0, nextb = KC;          // 384 then 768 then "never"
        for (int i = 0; i < nnz; ++i) {
            const int k = list[i];
            while (k >= nextb) {
                if (p == 0) { a0 = p0; a1 = p1; a2 = p2; a3 = p3; }
                else {
                    a0 = __fadd_rn(a0, p0); a1 = __fadd_rn(a1, p1);
                    a2 = __fadd_rn(a2, p2); a3 = __fadd_rn(a3, p3);
                }
                p0 = p1 = p2 = p3 = 0.f; ++p;
                nextb = (nextb == KC) ? 2 * KC : 100000;
            }
            const float4 w = *(const float4*)(W2T + (size_t)k * NHID + n);
            p0 = __fadd_rn(p0, w.x); p1 = __fadd_rn(p1, w.y);
            p2 = __fadd_rn(p2, w.z); p3 = __fadd_rn(p3, w.w);
        }
        while (p < 3) {                 // close remaining panels (K=800 -> 3)
            if (p == 0) { a0 = p0; a1 = p1; a2 = p2; a3 = p3; }
            else {
                a0 = __fadd_rn(a0, p0); a1 = __fadd_rn(a1, p1);
                a2 = __fadd_rn(a2, p2); a3 = __fadd_rn(a3, p3);
            }
            p0 = p1 = p2 = p3 = 0.f; ++p;
        }
        *(float4*)(Z + (size_t)row * NHID + n) = make_float4(a0, a1, a2, a3);
    }
}

// ---------------------------------------------------------------------------
// Layer-3 GEMM, float4 loads, chain preserved (folds at float4 idx 96/192).
// ---------------------------------------------------------------------------
__global__ __launch_bounds__(256)
void gemm3_f32(const float* __restrict__ S2, const float* __restrict__ W3,
               float* __restrict__ Z3, int rows)
{
    int gid = blockIdx.x * 256 + threadIdx.x;
    if (gid >= rows * NOUT) return;
    const int m = gid / NOUT;
    const int nn = gid % NOUT;
    const float* a = S2 + (size_t)m * NHID;
    const float* wr = W3 + (size_t)nn * NHID;

    float part = 0.0f, acc = 0.0f;
    int p = 0;
    for (int i = 0; i < NHID / 4; ++i) {
        if (i == 96 || i == 192) {
            acc = (p == 0) ? part : __fadd_rn(acc, part);
            part = 0.0f; ++p;
        }
        const v4f a4 = __builtin_nontemporal_load((const v4f*)(a + 4 * i));
        const float4 w4 = *(const float4*)(wr + 4 * i);
        part = __fmaf_rn(a4.x, w4.x, part);
        part = __fmaf_rn(a4.y, w4.y, part);
        part = __fmaf_rn(a4.z, w4.z, part);
        part = __fmaf_rn(a4.w, w4.w, part);
    }
    acc = (p == 0) ? part : __fadd_rn(acc, part);
    Z3[gid] = acc;
}

// ---------------------------------------------------------------------------
__global__ __launch_bounds__(256)
void lif_scan_small(const float* __restrict__ Z, const float* __restrict__ bias,
                    float* __restrict__ mcarry, float* __restrict__ Sout,
                    int CT, int t0)
{
    const int idx = blockIdx.x * blockDim.x + threadIdx.x;
    const int total = BATCH * NOUT;
    if (idx >= total) return;
    const int j = idx % NOUT;
    const float thr = 1.0f;
    const float bj = bias[j];

    float m = mcarry[idx];
    for (int ct = 0; ct < CT; ++ct) {
        float z = Z[(size_t)ct * total + idx];
        m = __fadd_rn(__fadd_rn(__fmul_rn(0.95f, m), z), bj);
        float s;
        if (m > thr) { s = 1.0f; m = 0.0f; }
        else         { s = 0.0f; }
        Sout[(size_t)(t0 + ct) * total + idx] = s;
    }
    mcarry[idx] = m;
}

// ---------------------------------------------------------------------------
__global__ __launch_bounds__(256)
void sum_t(const float* __restrict__ S3, float* __restrict__ out0)
{
    const int idx = blockIdx.x * blockDim.x + threadIdx.x;
    if (idx >= BATCH * NOUT) return;
    float s = 0.0f;
    for (int t = 0; t < TSTEPS; ++t)
        s += S3[(size_t)t * BATCH * NOUT + idx];
    out0[idx] = s;
}

// ---------------------------------------------------------------------------
extern "C" void kernel_launch(void* const* d_in, const int* in_sizes, int n_in,
                              void* d_out, int out_size, void* d_ws, size_t ws_size,
                              hipStream_t stream)
{
    const float* x       = (const float*)d_in[0];
    const float* W1      = (const float*)d_in[1];
    const float* b1      = (const float*)d_in[2];
    const float* W2      = (const float*)d_in[3];
    const float* b2      = (const float*)d_in[4];
    const float* W3      = (const float*)d_in[5];
    const float* b3      = (const float*)d_in[6];
    const float* budget1 = (const float*)d_in[7];
    const float* budget2 = (const float*)d_in[8];

    float* out  = (float*)d_out;
    float* out0 = out;
    float* out1 = out0 + BATCH * NOUT;
    float* out2 = out1 + (size_t)TSTEPS * BATCH * NHID;
    float* out3 = out2 + (size_t)TSTEPS * BATCH * NHID;

    const size_t nBH = (size_t)BATCH * NHID;     // 409600
    const size_t nBO = (size_t)BATCH * NOUT;     // 5120
    float* m1c = (float*)d_ws;
    float* m2c = m1c + nBH;
    float* m3c = m2c + nBH;
    float* w2t = m3c + nBO;
    unsigned long long* bmask = (unsigned long long*)(w2t + (size_t)NHID * NHID);
    float* Z = (float*)(bmask + (size_t)TSTEPS * BATCH * 13);

    const size_t fixedF = 2 * nBH + nBO + (size_t)NHID * NHID
                        + (size_t)TSTEPS * BATCH * 13 * 2;
    size_t availF = (ws_size / 4 > fixedF) ? (ws_size / 4 - fixedF) : 0;
    // per timestep: 2 Z-panels (layer 1) + Z3
    const size_t perT = (size_t)BATCH * (2 * NHID + NOUT);
    int CT = (int)(availF / perT);
    if (CT > TSTEPS) CT = TSTEPS;
    if (CT < 1) CT = 1;

    hipMemsetAsync(d_ws, 0, (2 * nBH + nBO) * sizeof(float), stream);

    {
        dim3 tg(25, 25);
        transpose800<<<tg, 256, 0, stream>>>(W2, w2t);
    }

    for (int t0 = 0; t0 < TSTEPS; t0 += CT) {
        int ct = TSTEPS - t0 < CT ? TSTEPS - t0 : CT;
        int Mrows = ct * BATCH;
        const size_t pstride = (size_t)ct * BATCH * NHID;
        float* Zp0 = Z;
        float* Zp1 = Z + pstride;
        float* Z3  = Z + 2 * pstride;
        const float* xc = x + (size_t)t0 * BATCH * NIN;

        // layer 1: two K-panels of x_chunk @ W1^T (P3 fused into lif)
        {
            dim3 grid(Mrows / 128, (NHID + 127) / 128);
            gemm_panel_f32<<<grid, 256, 0, stream>>>(xc, W1, Zp0, Mrows, NHID, NIN, 0,   384);
            gemm_panel_f32<<<grid, 256, 0, stream>>>(xc, W1, Zp1, Mrows, NHID, NIN, 384, 768);
        }
        lif_scan_hid1<<<BATCH, 256, 0, stream>>>(
            Zp0, Zp1, xc, W1, b1, budget1, m1c, out1, bmask, ct, t0);

        // layer 2: sparse Z = s1_chunk @ W2^T via bitmask (1 row/block)
        spmm_spikes<<<Mrows, 256, 0, stream>>>(bmask, w2t, Zp0, Mrows);
        lif_scan_hid2<<<BATCH, 256, 0, stream>>>(
            Zp0, b2, budget2, m2c, out2, ct, t0);

        // layer 3
        gemm3_f32<<<(Mrows * NOUT + 255) / 256, 256, 0, stream>>>(
            out2 + (size_t)t0 * BATCH * NHID, W3, Z3, Mrows);
        lif_scan_small<<<(BATCH * NOUT + 255) / 256, 256, 0, stream>>>(
            Z3, b3, m3c, out3, ct, t0);
    }

    sum_t<<<(BATCH * NOUT + 255) / 256, 256, 0, stream>>>(out3, out0);
}